// Round 7
// baseline (175.448 us; speedup 1.0000x reference)
//
#include <hip/hip_runtime.h>
#include <hip/hip_bf16.h>

typedef __hip_bfloat16 bf16;
typedef __attribute__((ext_vector_type(8))) short short8;   // 8 bf16 = 4 VGPRs
typedef __attribute__((ext_vector_type(4))) float f32x4;    // MFMA C/D frag

__device__ __forceinline__ short8 ld8(const void* p) { return *(const short8*)p; }
__device__ __forceinline__ void st8(void* p, short8 v) { *(short8*)p = v; }

// async global->LDS, 16B per lane: LDS dest = (wave-uniform) base + lane*16
__device__ __forceinline__ void async_cp16(bf16* lds, const bf16* g) {
    __builtin_amdgcn_global_load_lds(
        (const __attribute__((address_space(1))) unsigned int*)g,
        (__attribute__((address_space(3))) unsigned int*)lds, 16, 0, 0);
}

struct bf4 { bf16 a, b, c, d; };

// chunk-start table for the balanced causal k-split (chunk = 4 k-tiles):
// starts[c] = 34c - 2c^2 ; slot s = starts[c] + (i - 4c) for q-tile i >= 4c.
__constant__ int kChunkStart[9] = {0, 32, 60, 84, 104, 120, 132, 140, 144};

// ---------------------------------------------------------------------------
__global__ void cast_kernel(const float* __restrict__ s0, bf16* __restrict__ d0, int n0_,
                            const float* __restrict__ s1, bf16* __restrict__ d1, int n1_,
                            const float* __restrict__ s2, bf16* __restrict__ d2, int n2_,
                            const float* __restrict__ s3, bf16* __restrict__ d3, int n3_,
                            const float* __restrict__ s4, bf16* __restrict__ d4, int n4_) {
    const float* srcs[5] = {s0, s1, s2, s3, s4};
    bf16* dsts[5] = {d0, d1, d2, d3, d4};
    int ns[5] = {n0_, n1_, n2_, n3_, n4_};
    int stride = gridDim.x * blockDim.x;
    int t0 = blockIdx.x * blockDim.x + threadIdx.x;
#pragma unroll
    for (int a = 0; a < 5; ++a) {
        const float4* src = (const float4*)srcs[a];
        bf4* dst = (bf4*)dsts[a];
        int n4 = ns[a] >> 2;
        for (int i = t0; i < n4; i += stride) {
            float4 v = src[i];
            bf4 o = {__float2bfloat16(v.x), __float2bfloat16(v.y),
                     __float2bfloat16(v.z), __float2bfloat16(v.w)};
            dst[i] = o;
        }
    }
}

// ---------------------------------------------------------------------------
// Fused Q/K/V projection. A = hsb [M,K]. N-tiles: 0..15 -> Q (scaled 1/8),
// 16 -> K, 17 -> V (stored transposed). Tile 128x64, BK=64, 4 waves.
__global__ void qkv_proj_kernel(const bf16* __restrict__ A,
                                const bf16* __restrict__ Wq, const bf16* __restrict__ Wk,
                                const bf16* __restrict__ Wv,
                                const float* __restrict__ bq, const float* __restrict__ bk,
                                const float* __restrict__ bv,
                                bf16* __restrict__ qo, bf16* __restrict__ ko,
                                bf16* __restrict__ vto, int M, int K) {
    __shared__ __align__(16) bf16 As[128][64];
    __shared__ __align__(16) bf16 Bs[64][64];
    const int nt = blockIdx.x;
    const bf16* W;
    const float* bias;
    int mode, nw0;
    if (nt < 16)      { W = Wq; bias = bq; mode = 0; nw0 = nt * 64; }
    else if (nt == 16){ W = Wk; bias = bk; mode = 1; nw0 = 0; }
    else              { W = Wv; bias = bv; mode = 2; nw0 = 0; }

    const int tid = threadIdx.x;
    const int wave = tid >> 6, lane = tid & 63;
    const int l16 = lane & 15, quad = lane >> 4;
    const int m0 = blockIdx.y * 128;
    const int lr = lane >> 3, lsw = (lane & 7) ^ (lr & 7);

    f32x4 acc[2][4];
    const f32x4 z = {0.f, 0.f, 0.f, 0.f};
#pragma unroll
    for (int mi = 0; mi < 2; ++mi)
#pragma unroll
        for (int ni = 0; ni < 4; ++ni) acc[mi][ni] = z;

    for (int k0 = 0; k0 < K; k0 += 64) {
#pragma unroll
        for (int u = 0; u < 4; ++u) {
            int t = wave * 4 + u;
            async_cp16(&As[t * 8][0], A + (size_t)(m0 + t * 8 + lr) * K + k0 + lsw * 8);
        }
#pragma unroll
        for (int u = 0; u < 2; ++u) {
            int t = wave * 2 + u;
            async_cp16(&Bs[t * 8][0], W + (size_t)(nw0 + t * 8 + lr) * K + k0 + lsw * 8);
        }
        __syncthreads();

        short8 af[2][2], bfr[2][4];
#pragma unroll
        for (int mi = 0; mi < 2; ++mi)
#pragma unroll
            for (int kc = 0; kc < 2; ++kc) {
                int R = wave * 32 + mi * 16 + l16;
                int g = kc * 4 + quad;
                af[mi][kc] = ld8(&As[R][(g ^ (R & 7)) * 8]);
            }
#pragma unroll
        for (int ni = 0; ni < 4; ++ni)
#pragma unroll
            for (int kc = 0; kc < 2; ++kc) {
                int r = ni * 16 + l16;
                int g = kc * 4 + quad;
                bfr[kc][ni] = ld8(&Bs[r][(g ^ (r & 7)) * 8]);
            }
#pragma unroll
        for (int kc = 0; kc < 2; ++kc)
#pragma unroll
            for (int mi = 0; mi < 2; ++mi)
#pragma unroll
                for (int ni = 0; ni < 4; ++ni)
                    acc[mi][ni] = __builtin_amdgcn_mfma_f32_16x16x32_bf16(
                        af[mi][kc], bfr[kc][ni], acc[mi][ni], 0, 0, 0);
        __syncthreads();
    }

#pragma unroll
    for (int mi = 0; mi < 2; ++mi)
#pragma unroll
        for (int ni = 0; ni < 4; ++ni)
#pragma unroll
            for (int r = 0; r < 4; ++r) {
                int row = m0 + wave * 32 + mi * 16 + quad * 4 + r;
                int col = ni * 16 + l16; // 0..63 within tile
                float v = acc[mi][ni][r] + bias[nw0 + col];
                if (mode == 0)
                    qo[(size_t)row * 1024 + nt * 64 + col] = __float2bfloat16(v * 0.125f);
                else if (mode == 1)
                    ko[(size_t)row * 64 + col] = __float2bfloat16(v);
                else
                    vto[(size_t)col * M + row] = __float2bfloat16(v);
            }
}

// ---------------------------------------------------------------------------
// C[M,N] = A[M,K](bf16) @ W[N,K](bf16)^T + bias (fp32 out). 128x64 tile.
__global__ void gemm_bt_mfma(const bf16* __restrict__ A, const bf16* __restrict__ W,
                             const float* __restrict__ bias, float* __restrict__ C,
                             int M, int N, int K) {
    __shared__ __align__(16) bf16 As[128][64];
    __shared__ __align__(16) bf16 Bs[64][64];
    const int tid = threadIdx.x;
    const int wave = tid >> 6, lane = tid & 63;
    const int l16 = lane & 15, quad = lane >> 4;
    const int m0 = blockIdx.y * 128, n0 = blockIdx.x * 64;
    const int lr = lane >> 3, lsw = (lane & 7) ^ (lr & 7);

    f32x4 acc[2][4];
    const f32x4 z = {0.f, 0.f, 0.f, 0.f};
#pragma unroll
    for (int mi = 0; mi < 2; ++mi)
#pragma unroll
        for (int ni = 0; ni < 4; ++ni) acc[mi][ni] = z;

    for (int k0 = 0; k0 < K; k0 += 64) {
#pragma unroll
        for (int u = 0; u < 4; ++u) {
            int t = wave * 4 + u;
            async_cp16(&As[t * 8][0], A + (size_t)(m0 + t * 8 + lr) * K + k0 + lsw * 8);
        }
#pragma unroll
        for (int u = 0; u < 2; ++u) {
            int t = wave * 2 + u;
            async_cp16(&Bs[t * 8][0], W + (size_t)(n0 + t * 8 + lr) * K + k0 + lsw * 8);
        }
        __syncthreads();

        short8 af[2][2], bfr[2][4];
#pragma unroll
        for (int mi = 0; mi < 2; ++mi)
#pragma unroll
            for (int kc = 0; kc < 2; ++kc) {
                int R = wave * 32 + mi * 16 + l16;
                int g = kc * 4 + quad;
                af[mi][kc] = ld8(&As[R][(g ^ (R & 7)) * 8]);
            }
#pragma unroll
        for (int ni = 0; ni < 4; ++ni)
#pragma unroll
            for (int kc = 0; kc < 2; ++kc) {
                int r = ni * 16 + l16;
                int g = kc * 4 + quad;
                bfr[kc][ni] = ld8(&Bs[r][(g ^ (r & 7)) * 8]);
            }
#pragma unroll
        for (int kc = 0; kc < 2; ++kc)
#pragma unroll
            for (int mi = 0; mi < 2; ++mi)
#pragma unroll
                for (int ni = 0; ni < 4; ++ni)
                    acc[mi][ni] = __builtin_amdgcn_mfma_f32_16x16x32_bf16(
                        af[mi][kc], bfr[kc][ni], acc[mi][ni], 0, 0, 0);
        __syncthreads();
    }

#pragma unroll
    for (int mi = 0; mi < 2; ++mi)
#pragma unroll
        for (int ni = 0; ni < 4; ++ni)
#pragma unroll
            for (int r = 0; r < 4; ++r) {
                int row = m0 + wave * 32 + mi * 16 + quad * 4 + r;
                int col = n0 + ni * 16 + l16;
                C[(size_t)row * N + col] = acc[mi][ni][r] + bias[col];
            }
}

// ---------------------------------------------------------------------------
// Flash causal MQA phase A. Chunk = 4 k-tiles (256 keys); 144 slots/head
// (slot s -> chunk c, q-tile i via kChunkStart). Every block active, <=4
// iters. Double-buffered K/V; l-sum via ones-column MFMA (l16==0 lanes).
__global__ void flash_mfma_kernel(const bf16* __restrict__ Q, const bf16* __restrict__ Kg,
                                  const bf16* __restrict__ VT,
                                  float* __restrict__ Opart, float* __restrict__ MLpart,
                                  int S) {
    const int s = blockIdx.x;
    int c = 0;
#pragma unroll
    for (int cc = 1; cc < 8; ++cc)
        if (s >= kChunkStart[cc]) c = cc;
    const int i = s - kChunkStart[c] + 4 * c;

    __shared__ __align__(16) bf16 Ks[2][64][64]; // 16 KB, XOR-swizzled
    __shared__ __align__(16) bf16 Vt[2][64][64]; // 16 KB, XOR-swizzled
    __shared__ bf16 Ps[4][16][68];               // 8.7 KB, stride 68

    const int h = blockIdx.y;
    const int q0 = i * 64;
    const int tid = threadIdx.x;
    const int wave = tid >> 6, lane = tid & 63;
    const int l16 = lane & 15, quad = lane >> 4;
    const int lr = lane >> 3, lsw = (lane & 7) ^ (lr & 7);
    const int qrow = q0 + wave * 16;

    short8 qf[2];
#pragma unroll
    for (int kc = 0; kc < 2; ++kc)
        qf[kc] = ld8(Q + (size_t)(qrow + l16) * 1024 + h * 64 + kc * 32 + quad * 8);

    // ones B-frag: column n=0 (l16==0 lanes) = 1.0, else 0 -> P row-sums
    short8 onesf;
    {
        short o = (l16 == 0) ? (short)0x3F80 : (short)0;
        onesf[0]=o; onesf[1]=o; onesf[2]=o; onesf[3]=o;
        onesf[4]=o; onesf[5]=o; onesf[6]=o; onesf[7]=o;
    }

    f32x4 of[4];
    const f32x4 z = {0.f, 0.f, 0.f, 0.f};
#pragma unroll
    for (int dt = 0; dt < 4; ++dt) of[dt] = z;
    float m_run[4], l_run[4];
#pragma unroll
    for (int r = 0; r < 4; ++r) { m_run[r] = -1e30f; l_run[r] = 0.f; }

    const int jt0 = c * 4;
    const int jt1 = min(c * 4 + 4, i + 1);

    // prologue: stage jt0 into buf 0
    {
        const int j0 = jt0 * 64;
#pragma unroll
        for (int u = 0; u < 2; ++u) {
            int t = wave * 2 + u;
            async_cp16(&Ks[0][t * 8][0], Kg + (size_t)(j0 + t * 8 + lr) * 64 + lsw * 8);
            async_cp16(&Vt[0][t * 8][0], VT + (size_t)(t * 8 + lr) * S + j0 + lsw * 8);
        }
    }

    int buf = 0;
    for (int jt = jt0; jt < jt1; ++jt, buf ^= 1) {
        __syncthreads(); // staged data for jt visible
        if (jt + 1 < jt1) { // prefetch next tile into other buffer
            const int j0n = (jt + 1) * 64;
#pragma unroll
            for (int u = 0; u < 2; ++u) {
                int t = wave * 2 + u;
                async_cp16(&Ks[buf ^ 1][t * 8][0], Kg + (size_t)(j0n + t * 8 + lr) * 64 + lsw * 8);
                async_cp16(&Vt[buf ^ 1][t * 8][0], VT + (size_t)(t * 8 + lr) * S + j0n + lsw * 8);
            }
        }
        const int j0 = jt * 64;

        // S = Q K^T (Q pre-scaled by 1/8)
        f32x4 sc[4];
#pragma unroll
        for (int nt = 0; nt < 4; ++nt) {
            int R = nt * 16 + l16;
            sc[nt] = __builtin_amdgcn_mfma_f32_16x16x32_bf16(
                qf[0], ld8(&Ks[buf][R][(quad ^ (R & 7)) * 8]), z, 0, 0, 0);
            sc[nt] = __builtin_amdgcn_mfma_f32_16x16x32_bf16(
                qf[1], ld8(&Ks[buf][R][((4 + quad) ^ (R & 7)) * 8]), sc[nt], 0, 0, 0);
        }
        bool need_mask = (j0 + 63 > qrow);
        if (need_mask) {
#pragma unroll
            for (int nt = 0; nt < 4; ++nt)
#pragma unroll
                for (int r = 0; r < 4; ++r)
                    if (j0 + nt * 16 + l16 > qrow + quad * 4 + r) sc[nt][r] = -1e30f;
        }

        // row max via shfl over the 16-lane quad-group
        float tm[4];
#pragma unroll
        for (int r = 0; r < 4; ++r)
            tm[r] = fmaxf(fmaxf(sc[0][r], sc[1][r]), fmaxf(sc[2][r], sc[3][r]));
#pragma unroll
        for (int msk = 1; msk < 16; msk <<= 1)
#pragma unroll
            for (int r = 0; r < 4; ++r) tm[r] = fmaxf(tm[r], __shfl_xor(tm[r], msk));
        float alpha[4];
#pragma unroll
        for (int r = 0; r < 4; ++r) {
            float mn = fmaxf(m_run[r], tm[r]);
            alpha[r] = __expf(m_run[r] - mn);
            m_run[r] = mn;
        }
        // P = exp(S - m), pack to LDS (wave-private, no barrier)
#pragma unroll
        for (int nt = 0; nt < 4; ++nt)
#pragma unroll
            for (int r = 0; r < 4; ++r)
                Ps[wave][quad * 4 + r][nt * 16 + l16] =
                    __float2bfloat16(__expf(sc[nt][r] - m_run[r]));

#pragma unroll
        for (int dt = 0; dt < 4; ++dt)
#pragma unroll
            for (int r = 0; r < 4; ++r) of[dt][r] *= alpha[r];
        short8 pf[2];
#pragma unroll
        for (int kc = 0; kc < 2; ++kc) pf[kc] = ld8(&Ps[wave][l16][kc * 32 + quad * 8]);

        // l-sum via MFMA with ones column (result valid on l16==0 lanes)
        f32x4 lsum = __builtin_amdgcn_mfma_f32_16x16x32_bf16(pf[0], onesf, z, 0, 0, 0);
        lsum = __builtin_amdgcn_mfma_f32_16x16x32_bf16(pf[1], onesf, lsum, 0, 0, 0);
#pragma unroll
        for (int r = 0; r < 4; ++r) l_run[r] = l_run[r] * alpha[r] + lsum[r];

        // O += P V
#pragma unroll
        for (int dt = 0; dt < 4; ++dt) {
            int R = dt * 16 + l16;
            of[dt] = __builtin_amdgcn_mfma_f32_16x16x32_bf16(
                pf[0], ld8(&Vt[buf][R][(quad ^ (R & 7)) * 8]), of[dt], 0, 0, 0);
            of[dt] = __builtin_amdgcn_mfma_f32_16x16x32_bf16(
                pf[1], ld8(&Vt[buf][R][((4 + quad) ^ (R & 7)) * 8]), of[dt], 0, 0, 0);
        }
    }

    // partials at slot (s, h)
    float* Op = Opart + ((size_t)s * 16 + h) * 4096;
#pragma unroll
    for (int dt = 0; dt < 4; ++dt)
#pragma unroll
        for (int r = 0; r < 4; ++r) {
            int row = wave * 16 + quad * 4 + r;
            Op[row * 64 + dt * 16 + l16] = of[dt][r];
        }
    if (l16 == 0) {
        float* ML = MLpart + ((size_t)s * 16 + h) * 128;
#pragma unroll
        for (int r = 0; r < 4; ++r) {
            int row = wave * 16 + quad * 4 + r;
            ML[row] = m_run[r];
            ML[64 + row] = l_run[r];
        }
    }
}

// ---------------------------------------------------------------------------
// Merge <=8 partials per (q-tile i, head h) -> attn bf16 [S,1024] at (s,h*64+d).
__global__ void flash_merge_kernel(const float* __restrict__ Opart,
                                   const float* __restrict__ MLpart,
                                   bf16* __restrict__ attn) {
    const int i = blockIdx.x, h = blockIdx.y;
    const int nch = (i >> 2) + 1; // 1..8 chunks
    const int tid = threadIdx.x;
    const int row = tid >> 2, cg = (tid & 3) * 16;

    float m[8], l[8];
    for (int cc = 0; cc < nch; ++cc) {
        int s = kChunkStart[cc] + i - 4 * cc;
        const float* ML = MLpart + ((size_t)s * 16 + h) * 128;
        m[cc] = ML[row];
        l[cc] = ML[64 + row];
    }
    float M = m[0];
    for (int cc = 1; cc < nch; ++cc) M = fmaxf(M, m[cc]);
    float L = 0.f, w[8];
    for (int cc = 0; cc < nch; ++cc) {
        w[cc] = __expf(m[cc] - M);
        L += l[cc] * w[cc];
    }
    float inv = 1.f / L;

    float o[16];
#pragma unroll
    for (int j = 0; j < 16; ++j) o[j] = 0.f;
    for (int cc = 0; cc < nch; ++cc) {
        int s = kChunkStart[cc] + i - 4 * cc;
        const float* Op = Opart + ((size_t)s * 16 + h) * 4096 + row * 64 + cg;
#pragma unroll
        for (int j = 0; j < 16; ++j) o[j] += Op[j] * w[cc];
    }
    bf16* dst = attn + (size_t)(i * 64 + row) * 1024 + h * 64 + cg;
#pragma unroll
    for (int j = 0; j < 16; ++j) dst[j] = __float2bfloat16(o[j] * inv);
}

// ---------------------------------------------------------------------------
extern "C" void kernel_launch(void* const* d_in, const int* in_sizes, int n_in,
                              void* d_out, int out_size, void* d_ws, size_t ws_size,
                              hipStream_t stream) {
    const int S = 2048, E = 1024, D = 64;

    const float* hs = (const float*)d_in[0];
    const float* Wq = (const float*)d_in[2];
    const float* bq = (const float*)d_in[3];
    const float* Wk = (const float*)d_in[4];
    const float* bk = (const float*)d_in[5];
    const float* Wv = (const float*)d_in[6];
    const float* bv = (const float*)d_in[7];
    const float* Wo = (const float*)d_in[8];
    const float* bo = (const float*)d_in[9];
    float* out = (float*)d_out;

    bf16* ws = (bf16*)d_ws;
    bf16* hsb = ws;                       // S*E
    bf16* wqb = hsb + (size_t)S * E;      // E*E
    bf16* wkb = wqb + (size_t)E * E;      // D*E
    bf16* wvb = wkb + (size_t)D * E;      // D*E
    bf16* wob = wvb + (size_t)D * E;      // E*E
    bf16* q = wob + (size_t)E * E;        // S*E (holds Q * 1/8)
    bf16* kbuf = q + (size_t)S * E;       // S*D
    bf16* vt = kbuf + (size_t)S * D;      // D*S (transposed)
    bf16* attn = vt + (size_t)S * D;      // S*E
    float* Opart = (float*)(attn + (size_t)S * E); // 2304 slots * 4096 f32 (37.7 MB)
    float* MLpart = Opart + (size_t)2304 * 4096;   // 2304 * 128 f32 (1.2 MB)

    dim3 blk(256);
    cast_kernel<<<512, blk, 0, stream>>>(hs, hsb, S * E,
                                         Wq, wqb, E * E,
                                         Wk, wkb, D * E,
                                         Wv, wvb, D * E,
                                         Wo, wob, E * E);
    // fused Q/K/V projection (Q pre-scaled by 1/8)
    qkv_proj_kernel<<<dim3(18, S / 128), blk, 0, stream>>>(hsb, wqb, wkb, wvb,
                                                           bq, bk, bv,
                                                           q, kbuf, vt, S, E);
    // attention: balanced k-split (chunk=4) phase A + merge
    flash_mfma_kernel<<<dim3(144, 16), blk, 0, stream>>>(q, kbuf, vt, Opart, MLpart, S);
    flash_merge_kernel<<<dim3(32, 16), blk, 0, stream>>>(Opart, MLpart, attn);
    // output projection (fp32 out)
    gemm_bt_mfma<<<dim3(E / 64, S / 128), blk, 0, stream>>>(attn, wob, bo, out, S, E, E);
}